// Round 1
// baseline (2217.345 us; speedup 1.0000x reference)
//
#include <hip/hip_runtime.h>
#include <math.h>

#define N 1024
#define NWAVES 16   // 1024 threads / wave64

// ---------------------------------------------------------------------------
// Kernel 1: per-row argmax over all columns. One wave per row, coalesced.
// ---------------------------------------------------------------------------
__global__ __launch_bounds__(256) void init_rows(const float* __restrict__ C,
                                                 float* __restrict__ rowVal,
                                                 int* __restrict__ rowCol) {
    int wave = (blockIdx.x * blockDim.x + threadIdx.x) >> 6;  // global wave id = row
    int lane = threadIdx.x & 63;
    if (wave >= N) return;
    const float* row = C + (size_t)wave * N;
    float best = -INFINITY;
    int bestc = 0;
    #pragma unroll
    for (int k = 0; k < N / 64; ++k) {
        int col = lane + (k << 6);
        float v = row[col];
        if (v > best) { best = v; bestc = col; }   // strict > keeps smallest col
    }
    // 64-lane shuffle argmax, tie -> smaller col (matches first-index argmax)
    for (int m = 1; m < 64; m <<= 1) {
        float ov = __shfl_xor(best, m);
        int   oc = __shfl_xor(bestc, m);
        if (ov > best || (ov == best && oc < bestc)) { best = ov; bestc = oc; }
    }
    if (lane == 0) { rowVal[wave] = best; rowCol[wave] = bestc; }
}

// ---------------------------------------------------------------------------
// Kernel 2: sequential greedy loop, single block of 1024 threads (16 waves).
// rowVal[r] == -inf  <=>  row r already assigned.
// ---------------------------------------------------------------------------
__global__ __launch_bounds__(1024) void greedy_assign(const float* __restrict__ C,
                                                      const float* __restrict__ rowValIn,
                                                      const int* __restrict__ rowColIn,
                                                      int* __restrict__ out,
                                                      int doInit) {
    __shared__ float rowVal[N];
    __shared__ int   rowCol[N];
    __shared__ int   assignedCol[N];
    __shared__ unsigned long long colMask[N / 64];  // bit set = column used
    __shared__ float wbVal[NWAVES];
    __shared__ int   wbFlat[NWAVES];
    __shared__ int   bestFlatS;
    __shared__ int   invCnt[2];        // parity-double-buffered (no extra barrier)
    __shared__ int   invList[2][N];

    const int t = threadIdx.x;
    const int lane = t & 63;
    const int wave = t >> 6;

    if (t < N / 64) colMask[t] = 0ULL;
    if (t < 2) invCnt[t] = 0;

    if (doInit) {
        // fallback path (no workspace): wave w computes rows w, w+16, ...
        for (int r = wave; r < N; r += NWAVES) {
            const float* row = C + (size_t)r * N;
            float best = -INFINITY; int bestc = 0;
            #pragma unroll
            for (int k = 0; k < N / 64; ++k) {
                int col = lane + (k << 6);
                float v = row[col];
                if (v > best) { best = v; bestc = col; }
            }
            for (int m = 1; m < 64; m <<= 1) {
                float ov = __shfl_xor(best, m);
                int   oc = __shfl_xor(bestc, m);
                if (ov > best || (ov == best && oc < bestc)) { best = ov; bestc = oc; }
            }
            if (lane == 0) { rowVal[r] = best; rowCol[r] = bestc; }
        }
    } else {
        rowVal[t] = rowValIn[t];
        rowCol[t] = rowColIn[t];
    }
    __syncthreads();

    for (int iter = 0; iter < N; ++iter) {
        const int p = iter & 1;

        // ---- Phase A: block argmax over the 1024 cached row-bests ----------
        float v = rowVal[t];
        int flat = (t << 10) | rowCol[t];        // r*1024 + c, fits in 20 bits
        for (int m = 1; m < 64; m <<= 1) {
            float ov = __shfl_xor(v, m);
            int   of = __shfl_xor(flat, m);
            if (ov > v || (ov == v && of < flat)) { v = ov; flat = of; }
        }
        if (lane == 0) { wbVal[wave] = v; wbFlat[wave] = flat; }
        __syncthreads();                                           // B1

        // ---- Phase B: reduce the 16 wave candidates (wave 0) ---------------
        if (wave == 0) {
            float v2 = (lane < NWAVES) ? wbVal[lane] : -INFINITY;
            int   f2 = (lane < NWAVES) ? wbFlat[lane] : 0;
            for (int m = 1; m < NWAVES; m <<= 1) {
                float ov = __shfl_xor(v2, m);
                int   of = __shfl_xor(f2, m);
                if (ov > v2 || (ov == v2 && of < f2)) { v2 = ov; f2 = of; }
            }
            if (lane == 0) bestFlatS = f2;
        }
        __syncthreads();                                           // B2

        const int bf = bestFlatS;
        const int br = bf >> 10;
        const int bc = bf & (N - 1);

        // ---- Phase C: mark used, collect invalidated rows ------------------
        if (t == br) {
            rowVal[br] = -INFINITY;      // row retired
            assignedCol[br] = bc;
        }
        if (t == 0) {
            colMask[bc >> 6] |= 1ULL << (bc & 63);
            invCnt[p ^ 1] = 0;           // reset counter for NEXT iteration
        }
        // each thread owns row t; cached best died iff its col was just taken
        if (t != br && rowCol[t] == bc && rowVal[t] != -INFINITY) {
            int idx = atomicAdd(&invCnt[p], 1);
            invList[p][idx] = t;
        }
        __syncthreads();                                           // B3

        // ---- Phase D: wave-cooperative rebuild of invalidated rows ---------
        const int nInv = invCnt[p];
        for (int j = wave; j < nInv; j += NWAVES) {
            int r = invList[p][j];
            const float* row = C + (size_t)r * N;
            float best = -INFINITY; int bestc = 0;
            #pragma unroll
            for (int k = 0; k < N / 64; ++k) {
                int col = lane + (k << 6);
                bool used = (colMask[col >> 6] >> (col & 63)) & 1ULL;
                float val = row[col];
                if (!used && val > best) { best = val; bestc = col; }
            }
            for (int m = 1; m < 64; m <<= 1) {
                float ov = __shfl_xor(best, m);
                int   oc = __shfl_xor(bestc, m);
                if (ov > best || (ov == best && oc < bestc)) { best = ov; bestc = oc; }
            }
            if (lane == 0) { rowVal[r] = best; rowCol[r] = bestc; }
        }
        __syncthreads();                                           // B4
    }

    // ---- Epilogue: rows sorted ascending = identity; cols per row ----------
    out[t] = t;
    out[N + t] = assignedCol[t];
}

// ---------------------------------------------------------------------------
extern "C" void kernel_launch(void* const* d_in, const int* in_sizes, int n_in,
                              void* d_out, int out_size, void* d_ws, size_t ws_size,
                              hipStream_t stream) {
    const float* C = (const float*)d_in[0];
    int* out = (int*)d_out;

    if (ws_size >= (size_t)(N * 8)) {
        float* rv = (float*)d_ws;
        int*   rc = (int*)((char*)d_ws + (size_t)N * 4);
        init_rows<<<256, 256, 0, stream>>>(C, rv, rc);
        greedy_assign<<<1, 1024, 0, stream>>>(C, rv, rc, out, 0);
    } else {
        greedy_assign<<<1, 1024, 0, stream>>>(C, nullptr, nullptr, out, 1);
    }
}